// Round 3
// baseline (1922.390 us; speedup 1.0000x reference)
//
#include <hip/hip_runtime.h>
#include <hip/hip_bf16.h>
#include <stdint.h>

// Problem dims
#define BB 8
#define CC 512
#define NN 256
#define TT 32
#define JJ 2048           // B*N columns
#define KK 1024           // 2*C (x-part + h-part)

typedef _Float16 f16x8 __attribute__((ext_vector_type(8)));
typedef float f32x4 __attribute__((ext_vector_type(4)));

// ---------------- init: split weights fp16 hi/lo, bias sums, zero states ----------------
__global__ __launch_bounds__(256) void init_kernel(
    const float* __restrict__ Wx, const float* __restrict__ Wh,
    const float* __restrict__ bx, const float* __restrict__ bh,
    _Float16* __restrict__ Whi, _Float16* __restrict__ Wlo,
    float* __restrict__ bsum,
    _Float16* __restrict__ hhi0, _Float16* __restrict__ hlo0,
    float* __restrict__ cst)
{
    int tid = blockIdx.x * blockDim.x + threadIdx.x;
    int stride = gridDim.x * blockDim.x;
    // W[g][c][k], k<512 -> Wx, k>=512 -> Wh   (4*512*1024 = 2097152)
    for (int idx = tid; idx < 4 * 512 * 1024; idx += stride) {
        int k = idx & 1023;
        int gc = idx >> 10;
        float v = (k < 512) ? Wx[(gc << 9) + k] : Wh[(gc << 9) + (k - 512)];
        _Float16 hi = (_Float16)v;
        Whi[idx] = hi;
        Wlo[idx] = (_Float16)(v - (float)hi);
    }
    for (int idx = tid; idx < 2048; idx += stride) bsum[idx] = bx[idx] + bh[idx];
    unsigned int* hz1 = (unsigned int*)hhi0;
    unsigned int* hz2 = (unsigned int*)hlo0;
    for (int idx = tid; idx < (JJ * CC) / 2; idx += stride) { hz1[idx] = 0u; hz2[idx] = 0u; }
    for (int idx = tid; idx < JJ * CC; idx += stride) cst[idx] = 0.f;
}

// ---------------- x (B,C,N,T) fp32 -> xhi/xlo [t][j][f] fp16 ----------------
__global__ __launch_bounds__(256) void xpose_kernel(
    const float* __restrict__ x, _Float16* __restrict__ xhi, _Float16* __restrict__ xlo)
{
    int tid = threadIdx.x;
    int bidx = blockIdx.x;              // 4096 = (B*N)*2
    int f = ((bidx & 1) << 8) + tid;    // 0..511
    int bn = bidx >> 1;                 // j = b*256+n
    int b = bn >> 8, n = bn & 255;
    const float4* src = (const float4*)(x + (((size_t)(b << 9) + f) * 256 + n) * 32);
    float vals[32];
#pragma unroll
    for (int i = 0; i < 8; ++i) {
        float4 v = src[i];
        vals[4 * i + 0] = v.x; vals[4 * i + 1] = v.y;
        vals[4 * i + 2] = v.z; vals[4 * i + 3] = v.w;
    }
#pragma unroll
    for (int t = 0; t < 32; ++t) {
        size_t off = ((size_t)t * JJ + bn) * 512 + f;
        float v = vals[t];
        _Float16 hi = (_Float16)v;
        xhi[off] = hi;
        xlo[off] = (_Float16)(v - (float)hi);
    }
}

// ---------------- per-timestep fused split-fp16 GEMM + LSTM cell ----------------
// Z = Whi.ahi + Whi.alo + Wlo.ahi  (+bias); gates; c,h update (fp32); h re-split.
// Block: j-tile 64 (bx in 32), c-tile 64 (by in 8), 4 waves; wave w owns c-slice
// w*16, all 4 gates. MFMA 16x16x32 f16: A row=l&15,k=8*(l>>4)+e ; B col=l&15 same k;
// D col=l&15, row=4*(l>>4)+r.
__global__ __launch_bounds__(256) void step_kernel(
    const _Float16* __restrict__ xhi_t, const _Float16* __restrict__ xlo_t,   // [2048][512]
    const _Float16* __restrict__ hhi_in, const _Float16* __restrict__ hlo_in, // [2048][512]
    _Float16* __restrict__ hhi_out, _Float16* __restrict__ hlo_out,
    float* __restrict__ cst,            // [2048][512]
    const _Float16* __restrict__ Whi,   // [4][512][1024]
    const _Float16* __restrict__ Wlo,
    const float* __restrict__ bsum,     // [4][512]
    _Float16* __restrict__ hsTt)        // [2048][512]
{
    // LDS (uint4 units): Ahi[0,512) Alo[512,1024) Bhi[1024,3072) Blo[3072,5120) = 80 KB
    __shared__ uint4 lds4[5120];
    const int tid = threadIdx.x;
    const int l = tid & 63;
    const int w = tid >> 6;
    const int j0 = blockIdx.x * 64;
    const int c0 = blockIdx.y * 64;
    const int l15 = l & 15, l4 = l >> 4, l7 = l & 7;

    f32x4 acc[4][4];                    // [gate][jf]
#pragma unroll
    for (int g = 0; g < 4; ++g)
#pragma unroll
        for (int jf = 0; jf < 4; ++jf) acc[g][jf] = (f32x4){0.f, 0.f, 0.f, 0.f};

    for (int kk = 0; kk < 16; ++kk) {
        const int k0 = kk * 64;
        const _Float16* aHi; const _Float16* aLo; int aoff;
        if (k0 < 512) { aHi = xhi_t; aLo = xlo_t; aoff = k0; }
        else          { aHi = hhi_in; aLo = hlo_in; aoff = k0 - 512; }
        // ---- stage 80KB, 16B/chunk, XOR-swizzled (chunk ^= row&7) ----
#pragma unroll
        for (int i = 0; i < 2; ++i) {
            int q = tid + (i << 8);             // [0,512)
            int row = q >> 3, ch = q & 7;
            int slot = (row << 3) + (ch ^ (row & 7));
            size_t go = (size_t)(j0 + row) * 512 + aoff;
            lds4[slot]       = ((const uint4*)(aHi + go))[ch];
            lds4[512 + slot] = ((const uint4*)(aLo + go))[ch];
        }
#pragma unroll
        for (int i = 0; i < 8; ++i) {
            int q = tid + (i << 8);             // [0,2048)
            int row = q >> 3, ch = q & 7;       // row = g*64+c
            int g = row >> 6, c = row & 63;
            int slot = (row << 3) + (ch ^ (row & 7));
            size_t wo = ((size_t)(g * 512 + c0 + c) << 10) + k0;
            lds4[1024 + slot] = ((const uint4*)(Whi + wo))[ch];
            lds4[3072 + slot] = ((const uint4*)(Wlo + wo))[ch];
        }
        __syncthreads();
        // ---- 2 k-steps of K=32 each, 3 split terms ----
#pragma unroll
        for (int ks = 0; ks < 2; ++ks) {
            const int chb = (ks << 2) + l4;
            f16x8 ahi[4], alo[4], bhi[4], blo[4];
#pragma unroll
            for (int jf = 0; jf < 4; ++jf) {
                int row = (jf << 4) + l15;
                int s = (row << 3) + (chb ^ l7);
                ahi[jf] = __builtin_bit_cast(f16x8, lds4[s]);
                alo[jf] = __builtin_bit_cast(f16x8, lds4[512 + s]);
            }
#pragma unroll
            for (int g = 0; g < 4; ++g) {
                int row = (g << 6) + (w << 4) + l15;
                int s = (row << 3) + (chb ^ l7);
                bhi[g] = __builtin_bit_cast(f16x8, lds4[1024 + s]);
                blo[g] = __builtin_bit_cast(f16x8, lds4[3072 + s]);
            }
#pragma unroll
            for (int g = 0; g < 4; ++g)
#pragma unroll
                for (int jf = 0; jf < 4; ++jf) {
                    acc[g][jf] = __builtin_amdgcn_mfma_f32_16x16x32_f16(ahi[jf], bhi[g], acc[g][jf], 0, 0, 0);
                    acc[g][jf] = __builtin_amdgcn_mfma_f32_16x16x32_f16(alo[jf], bhi[g], acc[g][jf], 0, 0, 0);
                    acc[g][jf] = __builtin_amdgcn_mfma_f32_16x16x32_f16(ahi[jf], blo[g], acc[g][jf], 0, 0, 0);
                }
        }
        __syncthreads();
    }

    // ---- epilogue: gates + cell update (fp32), h re-split to hi/lo ----
    const int ccol = c0 + (w << 4) + l15;
    const float b0 = bsum[ccol], b1 = bsum[512 + ccol], b2 = bsum[1024 + ccol], b3 = bsum[1536 + ccol];
#pragma unroll
    for (int jf = 0; jf < 4; ++jf) {
#pragma unroll
        for (int r = 0; r < 4; ++r) {
            int j = j0 + (jf << 4) + (l4 << 2) + r;
            size_t idx = (size_t)j * 512 + ccol;
            float zi = acc[0][jf][r] + b0;
            float zf = acc[1][jf][r] + b1;
            float zo = acc[2][jf][r] + b2;
            float zg = acc[3][jf][r] + b3;
            float ig = 1.f / (1.f + expf(-zi));
            float fg = 1.f / (1.f + expf(-zf));
            float og = 1.f / (1.f + expf(-zo));
            float gg = tanhf(zg);
            float cn = fg * cst[idx] + ig * gg;
            cst[idx] = cn;
            float h = og * tanhf(cn);
            _Float16 hh = (_Float16)h;
            hhi_out[idx] = hh;
            hlo_out[idx] = (_Float16)(h - (float)hh);
            hsTt[idx] = hh;
        }
    }
}

// ---------------- hsT[t][j][c] fp16 -> out (B,C,N,T) fp32 ----------------
__global__ __launch_bounds__(256) void oxpose_kernel(
    const _Float16* __restrict__ hsT, float* __restrict__ out)
{
    int tid = threadIdx.x;
    int bidx = blockIdx.x;              // 4096 = (B*N)*2
    int c = ((bidx & 1) << 8) + tid;
    int bn = bidx >> 1;
    int b = bn >> 8, n = bn & 255;
    float vals[32];
#pragma unroll
    for (int t = 0; t < 32; ++t)
        vals[t] = (float)hsT[((size_t)t * JJ + bn) * 512 + c];
    float4* dst = (float4*)(out + (((size_t)(b << 9) + c) * 256 + n) * 32);
#pragma unroll
    for (int i = 0; i < 8; ++i) {
        float4 v;
        v.x = vals[4 * i + 0]; v.y = vals[4 * i + 1];
        v.z = vals[4 * i + 2]; v.w = vals[4 * i + 3];
        dst[i] = v;
    }
}

extern "C" void kernel_launch(void* const* d_in, const int* in_sizes, int n_in,
                              void* d_out, int out_size, void* d_ws, size_t ws_size,
                              hipStream_t stream)
{
    const float* x  = (const float*)d_in[0];
    const float* Wx = (const float*)d_in[1];
    const float* bx = (const float*)d_in[2];
    const float* Wh = (const float*)d_in[3];
    const float* bh = (const float*)d_in[4];
    float* out = (float*)d_out;

    char* ws = (char*)d_ws;
    // workspace layout (~212 MB total)
    _Float16* xhi  = (_Float16*)(ws);                    // 67108864
    _Float16* xlo  = (_Float16*)(ws + 67108864);         // 67108864
    _Float16* hsT  = (_Float16*)(ws + 134217728);        // 67108864
    _Float16* hhi  = (_Float16*)(ws + 201326592);        // 2*2097152 = 4194304 (double buf)
    _Float16* hlo  = (_Float16*)(ws + 205520896);        // 4194304
    float*    cst  = (float*)   (ws + 209715200);        // 4194304
    _Float16* Whi  = (_Float16*)(ws + 213909504);        // 4194304
    _Float16* Wlo  = (_Float16*)(ws + 218103808);        // 4194304
    float*    bsum = (float*)   (ws + 222298112);        // 8192

    init_kernel<<<2048, 256, 0, stream>>>(Wx, Wh, bx, bh, Whi, Wlo, bsum, hhi, hlo, cst);
    xpose_kernel<<<4096, 256, 0, stream>>>(x, xhi, xlo);
    for (int t = 0; t < 32; ++t) {
        const size_t hb_in  = (size_t)(t & 1) * (JJ * CC);
        const size_t hb_out = (size_t)((t + 1) & 1) * (JJ * CC);
        step_kernel<<<dim3(32, 8), 256, 0, stream>>>(
            xhi + (size_t)t * (JJ * CC), xlo + (size_t)t * (JJ * CC),
            hhi + hb_in, hlo + hb_in, hhi + hb_out, hlo + hb_out,
            cst, Whi, Wlo, bsum,
            hsT + (size_t)t * (JJ * CC));
    }
    oxpose_kernel<<<4096, 256, 0, stream>>>(hsT, out);
}

// Round 6
// 1532.945 us; speedup vs baseline: 1.2541x; 1.2541x over previous
//
#include <hip/hip_runtime.h>
#include <hip/hip_bf16.h>
#include <stdint.h>

typedef _Float16 f16x8 __attribute__((ext_vector_type(8)));
typedef float f32x16 __attribute__((ext_vector_type(16)));

#define MFMA __builtin_amdgcn_mfma_f32_32x32x16_f16

// ---- workspace layout (bytes), total ~212.3 MB ----
#define XP_OFF   0ull                 // 128MB: xp [t32][jblk16][kk16][jt4][ks2][sp2][l64] f16x8
#define HP_OFF   134217728ull         // 8MB:  hp [par2][jblk16][kkp16][jt4][ks2][sp2][l64] f16x8
#define WT_OFF   142606336ull         // 8MB:  Wt [nblk16][kk32][nt4][ks2][sp2][l64] f16x8
#define BI_OFF   150994944ull         // 256KB: bias [nblk16][nt4][l64][r16] f32
#define CS_OFF   151257088ull         // 4MB:  cst [jblk16][nblk16][jt4][nt4][l64] float4
#define HT_OFF   155451392ull         // 64MB: hsT [t32][j2048][c512] f16

__device__ __forceinline__ void gload16(const void* g, void* s) {
    __builtin_amdgcn_global_load_lds((const __attribute__((address_space(1))) void*)g,
                                     (__attribute__((address_space(3))) void*)s, 16, 0, 0);
}

// ---------------- init: pack weights into A-fragment layout, bias, zero state ----------------
__global__ __launch_bounds__(256) void init_kernel(
    const float* __restrict__ Wx, const float* __restrict__ Wh,
    const float* __restrict__ bx, const float* __restrict__ bh, char* __restrict__ ws)
{
    f16x8* Wt = (f16x8*)(ws + WT_OFF);
    float* bi = (float*)(ws + BI_OFF);
    float4* cs = (float4*)(ws + CS_OFF);
    uint4* hp0 = (uint4*)(ws + HP_OFF);
    int tid = blockIdx.x * 256 + threadIdx.x;
    int stride = gridDim.x * 256;
    // weights: 262144 (hi+lo pairs); A-frag: m=l&31 (n), k=8*(l>>5)+e
    for (int i = tid; i < 262144; i += stride) {
        int l = i & 63, ks = (i >> 6) & 1, nt = (i >> 7) & 3, kk = (i >> 9) & 31, nblk = i >> 14;
        int n = nblk * 128 + nt * 32 + (l & 31);
        int k = kk * 32 + ks * 16 + 8 * (l >> 5);
        int c = n >> 2, g = n & 3;
        const float* src = (k < 512) ? (Wx + ((size_t)(g * 512 + c)) * 512 + k)
                                     : (Wh + ((size_t)(g * 512 + c)) * 512 + (k - 512));
        f16x8 hi, lo;
#pragma unroll
        for (int e = 0; e < 8; ++e) {
            float v = src[e];
            _Float16 h = (_Float16)v;
            hi[e] = h; lo[e] = (_Float16)(v - (float)h);
        }
        size_t base = (size_t)((i >> 6) * 2) * 64 + (i & 63);
        Wt[base] = hi;
        Wt[base + 64] = lo;
    }
    // bias packed to D-frag rows: row(r,l) = (r&3)+8*(r>>2)+4*(l>>5)
    for (int i = tid; i < 65536; i += stride) {
        int r = i & 15, l = (i >> 4) & 63, nt = (i >> 10) & 3, nblk = i >> 12;
        int n = nblk * 128 + nt * 32 + (r & 3) + 8 * (r >> 2) + 4 * (l >> 5);
        int c = n >> 2, g = n & 3;
        bi[i] = bx[g * 512 + c] + bh[g * 512 + c];
    }
    for (int i = tid; i < 262144; i += stride) cs[i] = make_float4(0.f, 0.f, 0.f, 0.f);
    for (int i = tid; i < 262144; i += stride) hp0[i] = make_uint4(0u, 0u, 0u, 0u);
}

// ---------------- xpose: x (B,C,N,T) f32 -> xp packed B-frag hi/lo ----------------
__global__ __launch_bounds__(256) void xpose_kernel(const float* __restrict__ x, f16x8* __restrict__ xp)
{
    __shared__ float tile[8448];   // [f 8][j 32][t 33]
    int tid = threadIdx.x;
    int jblk = blockIdx.x, jt = blockIdx.y, fq = blockIdx.z;
    int jbase = jblk * 128 + jt * 32;
    for (int fg = 0; fg < 16; ++fg) {
        int fgg = fq * 16 + fg;
        {
            int jl = tid & 31, fo = tid >> 5;
            int j = jbase + jl, b = j >> 8, n = j & 255, f = fgg * 8 + fo;
            const float4* src = (const float4*)(x + (((size_t)(b * 512 + f)) * 256 + n) * 32);
            float* dst = &tile[(fo * 32 + jl) * 33];
#pragma unroll
            for (int i2 = 0; i2 < 8; ++i2) {
                float4 v = src[i2];
                dst[4 * i2 + 0] = v.x; dst[4 * i2 + 1] = v.y;
                dst[4 * i2 + 2] = v.z; dst[4 * i2 + 3] = v.w;
            }
        }
        __syncthreads();
        {
            int jl = tid & 31, tq = tid >> 5;
            int kk = fgg >> 2, ks = (fgg >> 1) & 1, hb = fgg & 1;
            int l = hb * 32 + jl;
#pragma unroll
            for (int ti = 0; ti < 4; ++ti) {
                int t = tq * 4 + ti;
                f16x8 hi, lo;
#pragma unroll
                for (int e = 0; e < 8; ++e) {
                    float v = tile[(e * 32 + jl) * 33 + t];
                    _Float16 h = (_Float16)v;
                    hi[e] = h; lo[e] = (_Float16)(v - (float)h);
                }
                size_t base = ((((size_t)t * 16 + jblk) * 16 + kk) * 4 + jt) * 4 + ks * 2;
                xp[(base + 0) * 64 + l] = hi;
                xp[(base + 1) * 64 + l] = lo;
            }
        }
        __syncthreads();
    }
}

// ---------------- per-timestep fused split-fp16 GEMM (32x32x16) + LSTM cell ----------------
// D[n=4c+g][j]: A-operand = weights (frag-packed, direct L2->VGPR), B-operand = activations
// (frag-packed, gload_lds staged, double-buffered). Block: n128 x j128, 4 waves (wn2 x wj2),
// wave tile n64 x j64 = 2x2 MFMA tiles. XCD-pinned: nblk = (bid&7)*2 + parity.
__global__ __launch_bounds__(256, 1) void step_kernel(
    const f16x8* __restrict__ xp_t,    // + t*262144
    const f16x8* __restrict__ hp_in,   // + (t&1)*262144
    f16x8* __restrict__ hp_out,
    const f16x8* __restrict__ Wt,
    const float4* __restrict__ bi4,    // bias [nblk][nt][l][4 float4]
    float4* __restrict__ cst4,
    _Float16* __restrict__ hsTt)       // + t*2048*512
{
    __shared__ f16x8 actl[2][1024];    // 32KB: [buf][jt4][ks2][sp2][l64]
    const int tid = threadIdx.x;
    const int l = tid & 63;
    const int w = tid >> 6;
    const int wn = w >> 1, wj = w & 1;
    const int bid = blockIdx.x;
    const int idx = bid >> 3;
    const int nblk = ((bid & 7) << 1) | (idx & 1);  // XCD-pinned weight panel
    const int jblk = idx >> 1;
    const int nt0 = wn * 2, jt0 = wj * 2;

    f32x16 acc00 = {0.f,0.f,0.f,0.f,0.f,0.f,0.f,0.f,0.f,0.f,0.f,0.f,0.f,0.f,0.f,0.f};
    f32x16 acc01 = acc00, acc10 = acc00, acc11 = acc00;
    f16x8 wtc0, wtc1, wtc2, wtc3, wtc4, wtc5, wtc6, wtc7;
    f16x8 wtn0, wtn1, wtn2, wtn3, wtn4, wtn5, wtn6, wtn7;

#define STAGE(bi_, kkv) do { \
    const f16x8* asrc = ((kkv) < 16) ? (xp_t + (size_t)(jblk * 16 + (kkv)) * 1024) \
                                     : (hp_in + (size_t)(jblk * 16 + ((kkv) - 16)) * 1024); \
    gload16(asrc + tid,       &actl[bi_][tid]); \
    gload16(asrc + tid + 256, &actl[bi_][tid + 256]); \
    gload16(asrc + tid + 512, &actl[bi_][tid + 512]); \
    gload16(asrc + tid + 768, &actl[bi_][tid + 768]); \
} while (0)

#define LOADW(P, kkv) do { \
    size_t wb = (size_t)((nblk * 32 + (kkv)) * 16 + nt0 * 4) * 64 + l; \
    P##0 = Wt[wb + 0 * 64]; P##1 = Wt[wb + 1 * 64]; P##2 = Wt[wb + 2 * 64]; P##3 = Wt[wb + 3 * 64]; \
    P##4 = Wt[wb + 4 * 64]; P##5 = Wt[wb + 5 * 64]; P##6 = Wt[wb + 6 * 64]; P##7 = Wt[wb + 7 * 64]; \
} while (0)

#define COMP_KS(bi_, whi0, wlo0, whi1, wlo1, ksv) do { \
    int ab = ((jt0 * 2 + (ksv)) * 2) * 64 + l; \
    f16x8 ahi0 = actl[bi_][ab], alo0 = actl[bi_][ab + 64]; \
    f16x8 ahi1 = actl[bi_][ab + 256], alo1 = actl[bi_][ab + 320]; \
    acc00 = MFMA(whi0, ahi0, acc00, 0, 0, 0); \
    acc00 = MFMA(wlo0, ahi0, acc00, 0, 0, 0); \
    acc00 = MFMA(whi0, alo0, acc00, 0, 0, 0); \
    acc01 = MFMA(whi0, ahi1, acc01, 0, 0, 0); \
    acc01 = MFMA(wlo0, ahi1, acc01, 0, 0, 0); \
    acc01 = MFMA(whi0, alo1, acc01, 0, 0, 0); \
    acc10 = MFMA(whi1, ahi0, acc10, 0, 0, 0); \
    acc10 = MFMA(wlo1, ahi0, acc10, 0, 0, 0); \
    acc10 = MFMA(whi1, alo0, acc10, 0, 0, 0); \
    acc11 = MFMA(whi1, ahi1, acc11, 0, 0, 0); \
    acc11 = MFMA(wlo1, ahi1, acc11, 0, 0, 0); \
    acc11 = MFMA(whi1, alo1, acc11, 0, 0, 0); \
} while (0)

#define COMPUTE(bi_, P) do { \
    COMP_KS(bi_, P##0, P##1, P##4, P##5, 0); \
    COMP_KS(bi_, P##2, P##3, P##6, P##7, 1); \
} while (0)

    STAGE(0, 0); LOADW(wtc, 0);
    __syncthreads();
    for (int kk2 = 0; kk2 < 16; ++kk2) {
        const int kkA = kk2 * 2;
        STAGE(1, kkA + 1); LOADW(wtn, kkA + 1);
        COMPUTE(0, wtc);
        __syncthreads();
        if (kk2 < 15) { STAGE(0, kkA + 2); LOADW(wtc, kkA + 2); }
        COMPUTE(1, wtn);
        __syncthreads();
    }

    // ---- epilogue: gates, cell update, h re-split + packed writes ----
    const int p = l >> 5;
#define GATE(accV, q, bq, coldc, cnoutc, hqv) do { \
    float zi = accV[4 * (q) + 0] + bq.x; \
    float zf = accV[4 * (q) + 1] + bq.y; \
    float zo = accV[4 * (q) + 2] + bq.z; \
    float zg = accV[4 * (q) + 3] + bq.w; \
    float ig = 1.f / (1.f + expf(-zi)); \
    float fg = 1.f / (1.f + expf(-zf)); \
    float og = 1.f / (1.f + expf(-zo)); \
    float gg = tanhf(zg); \
    float cn = fg * coldc + ig * gg; \
    cnoutc = cn; \
    hqv = og * tanhf(cn); \
} while (0)

#define EPI(accV, ntl, jtl) do { \
    int nt = nt0 + (ntl), jt = jt0 + (jtl); \
    size_t bb = ((size_t)(nblk * 4 + nt) * 64 + l) * 4; \
    float4 bq0 = bi4[bb + 0], bq1 = bi4[bb + 1], bq2 = bi4[bb + 2], bq3 = bi4[bb + 3]; \
    size_t ci = (((size_t)(jblk * 16 + nblk) * 4 + jt) * 4 + nt) * 64 + l; \
    float4 cold = cst4[ci]; \
    float4 cnew; \
    float hq0, hq1, hq2, hq3; \
    GATE(accV, 0, bq0, cold.x, cnew.x, hq0); \
    GATE(accV, 1, bq1, cold.y, cnew.y, hq1); \
    GATE(accV, 2, bq2, cold.z, cnew.z, hq2); \
    GATE(accV, 3, bq3, cold.w, cnew.w, hq3); \
    cst4[ci] = cnew; \
    float hr0 = __shfl_xor(hq0, 32); \
    float hr1 = __shfl_xor(hq1, 32); \
    float hr2 = __shfl_xor(hq2, 32); \
    float hr3 = __shfl_xor(hq3, 32); \
    float e0 = p ? hr0 : hq0, e1 = p ? hq0 : hr0; \
    float e2 = p ? hr1 : hq1, e3 = p ? hq1 : hr1; \
    float e4 = p ? hr2 : hq2, e5 = p ? hq2 : hr2; \
    float e6 = p ? hr3 : hq3, e7 = p ? hq3 : hr3; \
    f16x8 hhi, hlo; \
    hhi[0] = (_Float16)e0; hhi[1] = (_Float16)e1; hhi[2] = (_Float16)e2; hhi[3] = (_Float16)e3; \
    hhi[4] = (_Float16)e4; hhi[5] = (_Float16)e5; hhi[6] = (_Float16)e6; hhi[7] = (_Float16)e7; \
    hlo[0] = (_Float16)(e0 - (float)hhi[0]); hlo[1] = (_Float16)(e1 - (float)hhi[1]); \
    hlo[2] = (_Float16)(e2 - (float)hhi[2]); hlo[3] = (_Float16)(e3 - (float)hhi[3]); \
    hlo[4] = (_Float16)(e4 - (float)hhi[4]); hlo[5] = (_Float16)(e5 - (float)hhi[5]); \
    hlo[6] = (_Float16)(e6 - (float)hhi[6]); hlo[7] = (_Float16)(e7 - (float)hhi[7]); \
    if (p == (nt & 1)) { \
        size_t hb = ((((size_t)(jblk * 16 + nblk) * 4 + jt) * 2 + (nt >> 1))) * 2; \
        hp_out[(hb + 0) * 64 + l] = hhi; \
        hp_out[(hb + 1) * 64 + l] = hlo; \
        int j = jblk * 128 + jt * 32 + (l & 31); \
        int c0 = nblk * 32 + nt * 8; \
        *(f16x8*)(hsTt + (size_t)j * 512 + c0) = hhi; \
    } \
} while (0)

    EPI(acc00, 0, 0);
    EPI(acc01, 0, 1);
    EPI(acc10, 1, 0);
    EPI(acc11, 1, 1);
}

// ---------------- hsT[t][j][c] f16 -> out (B,C,N,T) f32 ----------------
__global__ __launch_bounds__(256) void oxpose_kernel(
    const _Float16* __restrict__ hsT, float* __restrict__ out)
{
    int tid = threadIdx.x;
    int bidx = blockIdx.x;              // 4096 = (B*N)*2
    int c = ((bidx & 1) << 8) + tid;
    int bn = bidx >> 1;
    int b = bn >> 8, n = bn & 255;
    float vals[32];
#pragma unroll
    for (int t = 0; t < 32; ++t)
        vals[t] = (float)hsT[((size_t)t * 2048 + bn) * 512 + c];
    float4* dst = (float4*)(out + (((size_t)(b * 512 + c)) * 256 + n) * 32);
#pragma unroll
    for (int i = 0; i < 8; ++i) {
        float4 v;
        v.x = vals[4 * i + 0]; v.y = vals[4 * i + 1];
        v.z = vals[4 * i + 2]; v.w = vals[4 * i + 3];
        dst[i] = v;
    }
}

extern "C" void kernel_launch(void* const* d_in, const int* in_sizes, int n_in,
                              void* d_out, int out_size, void* d_ws, size_t ws_size,
                              hipStream_t stream)
{
    const float* x  = (const float*)d_in[0];
    const float* Wx = (const float*)d_in[1];
    const float* bx = (const float*)d_in[2];
    const float* Wh = (const float*)d_in[3];
    const float* bh = (const float*)d_in[4];
    float* out = (float*)d_out;

    char* ws = (char*)d_ws;
    f16x8*  xp   = (f16x8*)(ws + XP_OFF);
    f16x8*  hp   = (f16x8*)(ws + HP_OFF);
    f16x8*  Wt   = (f16x8*)(ws + WT_OFF);
    float4* bi4  = (float4*)(ws + BI_OFF);
    float4* cst4 = (float4*)(ws + CS_OFF);
    _Float16* hsT = (_Float16*)(ws + HT_OFF);

    init_kernel<<<2048, 256, 0, stream>>>(Wx, Wh, bx, bh, ws);
    xpose_kernel<<<dim3(16, 4, 4), 256, 0, stream>>>(x, xp);
    for (int t = 0; t < 32; ++t) {
        step_kernel<<<256, 256, 0, stream>>>(
            xp + (size_t)t * 262144,
            hp + (size_t)(t & 1) * 262144,
            hp + (size_t)((t + 1) & 1) * 262144,
            Wt, bi4, cst4,
            hsT + (size_t)t * 2048 * 512);
    }
    oxpose_kernel<<<4096, 256, 0, stream>>>(hsT, out);
}

// Round 10
// 1395.697 us; speedup vs baseline: 1.3774x; 1.0983x over previous
//
#include <hip/hip_runtime.h>
#include <hip/hip_bf16.h>
#include <stdint.h>

typedef _Float16 f16x8 __attribute__((ext_vector_type(8)));
typedef float f32x16 __attribute__((ext_vector_type(16)));

#define MFMA __builtin_amdgcn_mfma_f32_32x32x16_f16

// ---- workspace layout (bytes), total ~212.3 MB ----
#define XP_OFF   0ull                 // 128MB: xp [t32][jblk16][kk16][jt4][ks2][sp2][l64] f16x8
#define HP_OFF   134217728ull         // 8MB:  hp [par2][jblk16][kkp16][jt4][ks2][sp2][l64] f16x8
#define WT_OFF   142606336ull         // 8MB:  Wt [nblk16][kk32][nt4][ks2][sp2][l64] f16x8
#define BI_OFF   150994944ull         // 256KB: bias [nblk16][nt4][l64][r16] f32
#define CS_OFF   151257088ull         // 4MB:  cst [jblk16][nblk16][jt4][nt4][l64] float4
#define HT_OFF   155451392ull         // 64MB: hsT [t32][j2048][c512] f16

__device__ __forceinline__ void gload16(const void* g, void* s) {
    __builtin_amdgcn_global_load_lds((const __attribute__((address_space(1))) void*)g,
                                     (__attribute__((address_space(3))) void*)s, 16, 0, 0);
}

// ---------------- init: pack weights into A-fragment layout, bias, zero state ----------------
__global__ __launch_bounds__(256) void init_kernel(
    const float* __restrict__ Wx, const float* __restrict__ Wh,
    const float* __restrict__ bx, const float* __restrict__ bh, char* __restrict__ ws)
{
    f16x8* Wt = (f16x8*)(ws + WT_OFF);
    float* bi = (float*)(ws + BI_OFF);
    float4* cs = (float4*)(ws + CS_OFF);
    uint4* hp0 = (uint4*)(ws + HP_OFF);
    int tid = blockIdx.x * 256 + threadIdx.x;
    int stride = gridDim.x * 256;
    // weights: 262144 (hi+lo pairs); A-frag: m=l&31 (n), k=8*(l>>5)+e
    for (int i = tid; i < 262144; i += stride) {
        int l = i & 63, ks = (i >> 6) & 1, nt = (i >> 7) & 3, kk = (i >> 9) & 31, nblk = i >> 14;
        int n = nblk * 128 + nt * 32 + (l & 31);
        int k = kk * 32 + ks * 16 + 8 * (l >> 5);
        int c = n >> 2, g = n & 3;
        const float* src = (k < 512) ? (Wx + ((size_t)(g * 512 + c)) * 512 + k)
                                     : (Wh + ((size_t)(g * 512 + c)) * 512 + (k - 512));
        f16x8 hi, lo;
#pragma unroll
        for (int e = 0; e < 8; ++e) {
            float v = src[e];
            _Float16 h = (_Float16)v;
            hi[e] = h; lo[e] = (_Float16)(v - (float)h);
        }
        size_t base = (size_t)((i >> 6) * 2) * 64 + (i & 63);
        Wt[base] = hi;
        Wt[base + 64] = lo;
    }
    // bias packed to D-frag rows: row(r,l) = (r&3)+8*(r>>2)+4*(l>>5)
    for (int i = tid; i < 65536; i += stride) {
        int r = i & 15, l = (i >> 4) & 63, nt = (i >> 10) & 3, nblk = i >> 12;
        int n = nblk * 128 + nt * 32 + (r & 3) + 8 * (r >> 2) + 4 * (l >> 5);
        int c = n >> 2, g = n & 3;
        bi[i] = bx[g * 512 + c] + bh[g * 512 + c];
    }
    for (int i = tid; i < 262144; i += stride) cs[i] = make_float4(0.f, 0.f, 0.f, 0.f);
    for (int i = tid; i < 262144; i += stride) hp0[i] = make_uint4(0u, 0u, 0u, 0u);
}

// ---------------- xpose: x (B,C,N,T) f32 -> xp packed B-frag hi/lo ----------------
// grid (16,4,64): one (jblk, jt, fgg) tile per block -> 4096 blocks, 4/CU.
__global__ __launch_bounds__(256) void xpose_kernel(const float* __restrict__ x, f16x8* __restrict__ xp)
{
    __shared__ float tile[8448];   // [f 8][j 32][t 33]
    int tid = threadIdx.x;
    int jblk = blockIdx.x, jt = blockIdx.y, fgg = blockIdx.z;  // fgg 0..63
    int jbase = jblk * 128 + jt * 32;
    {
        int jl = tid & 31, fo = tid >> 5;
        int j = jbase + jl, b = j >> 8, n = j & 255, f = fgg * 8 + fo;
        const float4* src = (const float4*)(x + (((size_t)(b * 512 + f)) * 256 + n) * 32);
        float* dst = &tile[(fo * 32 + jl) * 33];
#pragma unroll
        for (int i2 = 0; i2 < 8; ++i2) {
            float4 v = src[i2];
            dst[4 * i2 + 0] = v.x; dst[4 * i2 + 1] = v.y;
            dst[4 * i2 + 2] = v.z; dst[4 * i2 + 3] = v.w;
        }
    }
    __syncthreads();
    {
        int jl = tid & 31, tq = tid >> 5;
        int kk = fgg >> 2, ks = (fgg >> 1) & 1, hb = fgg & 1;
        int l = hb * 32 + jl;
#pragma unroll
        for (int ti = 0; ti < 4; ++ti) {
            int t = tq * 4 + ti;
            f16x8 hi, lo;
#pragma unroll
            for (int e = 0; e < 8; ++e) {
                float v = tile[(e * 32 + jl) * 33 + t];
                _Float16 h = (_Float16)v;
                hi[e] = h; lo[e] = (_Float16)(v - (float)h);
            }
            size_t base = ((((size_t)t * 16 + jblk) * 16 + kk) * 4 + jt) * 4 + ks * 2;
            xp[(base + 0) * 64 + l] = hi;
            xp[(base + 1) * 64 + l] = lo;
        }
    }
}

// ---------------- per-timestep fused split-fp16 GEMM (32x32x16) + LSTM cell ----------------
// D[n=4c+g][j]: A = weights (frag-packed, L2->VGPR direct), B = activations (frag-packed,
// gload_lds, double-buffered). Block: n64 x j128, 4 waves (wn2 x wj2); wave: nt fixed,
// 2 j-tiles. Grid 512 = 2 blocks/CU. XCD-pinned weight panels: nblk4 = (bid&7)*4 + idx&3.
__global__ __launch_bounds__(256, 2) void step_kernel(
    const f16x8* __restrict__ xp_t,    // + t*262144
    const f16x8* __restrict__ hp_in,   // + (t&1)*262144
    f16x8* __restrict__ hp_out,
    const f16x8* __restrict__ Wt,
    const float4* __restrict__ bi4,    // bias [nblk][nt][l][4 float4]
    float4* __restrict__ cst4,
    _Float16* __restrict__ hsTt)       // + t*2048*512
{
    __shared__ f16x8 actl[2][1024];    // 32KB: [buf][jt4][ks2][sp2][l64]
    const int tid = threadIdx.x;
    const int l = tid & 63;
    const int w = tid >> 6;
    const int wn = w >> 1, wj = w & 1;
    const int bid = blockIdx.x;
    const int idx = bid >> 3;
    const int nblk4 = ((bid & 7) << 2) | (idx & 3);  // n64 panel, XCD-pinned
    const int jblk = idx >> 2;
    const int nblk = nblk4 >> 1;
    const int nt = ((nblk4 & 1) << 1) | wn;          // this wave's n32 tile (0..3)
    const int jt0 = wj * 2;

    f32x16 acc0 = {0.f,0.f,0.f,0.f,0.f,0.f,0.f,0.f,0.f,0.f,0.f,0.f,0.f,0.f,0.f,0.f};
    f32x16 acc1 = acc0;
    f16x8 wtc0, wtc1, wtc2, wtc3;
    f16x8 wtn0, wtn1, wtn2, wtn3;

#define STAGE(bi_, kkv) do { \
    const f16x8* asrc = ((kkv) < 16) ? (xp_t + (size_t)(jblk * 16 + (kkv)) * 1024) \
                                     : (hp_in + (size_t)(jblk * 16 + ((kkv) - 16)) * 1024); \
    gload16(asrc + tid,       &actl[bi_][tid]); \
    gload16(asrc + tid + 256, &actl[bi_][tid + 256]); \
    gload16(asrc + tid + 512, &actl[bi_][tid + 512]); \
    gload16(asrc + tid + 768, &actl[bi_][tid + 768]); \
} while (0)

#define LOADW(P, kkv) do { \
    size_t wb = (size_t)((nblk * 32 + (kkv)) * 16 + nt * 4) * 64 + l; \
    P##0 = Wt[wb + 0 * 64]; P##1 = Wt[wb + 1 * 64]; \
    P##2 = Wt[wb + 2 * 64]; P##3 = Wt[wb + 3 * 64]; \
} while (0)

#define COMP_KS(bi_, whi, wlo, ksv) do { \
    int ab = ((jt0 * 2 + (ksv)) * 2) * 64 + l; \
    f16x8 ahi0 = actl[bi_][ab], alo0 = actl[bi_][ab + 64]; \
    f16x8 ahi1 = actl[bi_][ab + 256], alo1 = actl[bi_][ab + 320]; \
    acc0 = MFMA(whi, ahi0, acc0, 0, 0, 0); \
    acc0 = MFMA(wlo, ahi0, acc0, 0, 0, 0); \
    acc0 = MFMA(whi, alo0, acc0, 0, 0, 0); \
    acc1 = MFMA(whi, ahi1, acc1, 0, 0, 0); \
    acc1 = MFMA(wlo, ahi1, acc1, 0, 0, 0); \
    acc1 = MFMA(whi, alo1, acc1, 0, 0, 0); \
} while (0)

#define COMPUTE(bi_, P) do { \
    COMP_KS(bi_, P##0, P##1, 0); \
    COMP_KS(bi_, P##2, P##3, 1); \
} while (0)

    STAGE(0, 0); LOADW(wtc, 0);
    __syncthreads();
    for (int kk2 = 0; kk2 < 16; ++kk2) {
        const int kkA = kk2 * 2;
        STAGE(1, kkA + 1); LOADW(wtn, kkA + 1);
        COMPUTE(0, wtc);
        __syncthreads();
        if (kk2 < 15) { STAGE(0, kkA + 2); LOADW(wtc, kkA + 2); }
        COMPUTE(1, wtn);
        __syncthreads();
    }

    // ---- epilogue: gates, cell update, h re-split + packed writes ----
    const int p = l >> 5;
#define GATE(accV, q, bq, coldc, cnoutc, hqv) do { \
    float zi = accV[4 * (q) + 0] + bq.x; \
    float zf = accV[4 * (q) + 1] + bq.y; \
    float zo = accV[4 * (q) + 2] + bq.z; \
    float zg = accV[4 * (q) + 3] + bq.w; \
    float ig = 1.f / (1.f + expf(-zi)); \
    float fg = 1.f / (1.f + expf(-zf)); \
    float og = 1.f / (1.f + expf(-zo)); \
    float gg = tanhf(zg); \
    float cn = fg * coldc + ig * gg; \
    cnoutc = cn; \
    hqv = og * tanhf(cn); \
} while (0)

#define EPI(accV, jtl) do { \
    int jt = jt0 + (jtl); \
    size_t bb = ((size_t)(nblk * 4 + nt) * 64 + l) * 4; \
    float4 bq0 = bi4[bb + 0], bq1 = bi4[bb + 1], bq2 = bi4[bb + 2], bq3 = bi4[bb + 3]; \
    size_t ci = (((size_t)(jblk * 16 + nblk) * 4 + jt) * 4 + nt) * 64 + l; \
    float4 cold = cst4[ci]; \
    float4 cnew; \
    float hq0, hq1, hq2, hq3; \
    GATE(accV, 0, bq0, cold.x, cnew.x, hq0); \
    GATE(accV, 1, bq1, cold.y, cnew.y, hq1); \
    GATE(accV, 2, bq2, cold.z, cnew.z, hq2); \
    GATE(accV, 3, bq3, cold.w, cnew.w, hq3); \
    cst4[ci] = cnew; \
    float hr0 = __shfl_xor(hq0, 32); \
    float hr1 = __shfl_xor(hq1, 32); \
    float hr2 = __shfl_xor(hq2, 32); \
    float hr3 = __shfl_xor(hq3, 32); \
    float e0 = p ? hr0 : hq0, e1 = p ? hq0 : hr0; \
    float e2 = p ? hr1 : hq1, e3 = p ? hq1 : hr1; \
    float e4 = p ? hr2 : hq2, e5 = p ? hq2 : hr2; \
    float e6 = p ? hr3 : hq3, e7 = p ? hq3 : hr3; \
    f16x8 hhi, hlo; \
    hhi[0] = (_Float16)e0; hhi[1] = (_Float16)e1; hhi[2] = (_Float16)e2; hhi[3] = (_Float16)e3; \
    hhi[4] = (_Float16)e4; hhi[5] = (_Float16)e5; hhi[6] = (_Float16)e6; hhi[7] = (_Float16)e7; \
    hlo[0] = (_Float16)(e0 - (float)hhi[0]); hlo[1] = (_Float16)(e1 - (float)hhi[1]); \
    hlo[2] = (_Float16)(e2 - (float)hhi[2]); hlo[3] = (_Float16)(e3 - (float)hhi[3]); \
    hlo[4] = (_Float16)(e4 - (float)hhi[4]); hlo[5] = (_Float16)(e5 - (float)hhi[5]); \
    hlo[6] = (_Float16)(e6 - (float)hhi[6]); hlo[7] = (_Float16)(e7 - (float)hhi[7]); \
    if (p == (nt & 1)) { \
        size_t hb = ((((size_t)(jblk * 16 + nblk) * 4 + jt) * 2 + (nt >> 1))) * 2; \
        hp_out[(hb + 0) * 64 + l] = hhi; \
        hp_out[(hb + 1) * 64 + l] = hlo; \
        int j = jblk * 128 + jt * 32 + (l & 31); \
        int c0 = nblk * 32 + nt * 8; \
        *(f16x8*)(hsTt + (size_t)j * 512 + c0) = hhi; \
    } \
} while (0)

    EPI(acc0, 0);
    EPI(acc1, 1);
}

// ---------------- hsT[t][j][c] f16 -> out (B,C,N,T) f32 ----------------
__global__ __launch_bounds__(256) void oxpose_kernel(
    const _Float16* __restrict__ hsT, float* __restrict__ out)
{
    int tid = threadIdx.x;
    int bidx = blockIdx.x;              // 4096 = (B*N)*2
    int c = ((bidx & 1) << 8) + tid;
    int bn = bidx >> 1;
    int b = bn >> 8, n = bn & 255;
    float vals[32];
#pragma unroll
    for (int t = 0; t < 32; ++t)
        vals[t] = (float)hsT[((size_t)t * 2048 + bn) * 512 + c];
    float4* dst = (float4*)(out + (((size_t)(b * 512 + c)) * 256 + n) * 32);
#pragma unroll
    for (int i = 0; i < 8; ++i) {
        float4 v;
        v.x = vals[4 * i + 0]; v.y = vals[4 * i + 1];
        v.z = vals[4 * i + 2]; v.w = vals[4 * i + 3];
        dst[i] = v;
    }
}

extern "C" void kernel_launch(void* const* d_in, const int* in_sizes, int n_in,
                              void* d_out, int out_size, void* d_ws, size_t ws_size,
                              hipStream_t stream)
{
    const float* x  = (const float*)d_in[0];
    const float* Wx = (const float*)d_in[1];
    const float* bx = (const float*)d_in[2];
    const float* Wh = (const float*)d_in[3];
    const float* bh = (const float*)d_in[4];
    float* out = (float*)d_out;

    char* ws = (char*)d_ws;
    f16x8*  xp   = (f16x8*)(ws + XP_OFF);
    f16x8*  hp   = (f16x8*)(ws + HP_OFF);
    f16x8*  Wt   = (f16x8*)(ws + WT_OFF);
    float4* bi4  = (float4*)(ws + BI_OFF);
    float4* cst4 = (float4*)(ws + CS_OFF);
    _Float16* hsT = (_Float16*)(ws + HT_OFF);

    init_kernel<<<2048, 256, 0, stream>>>(Wx, Wh, bx, bh, ws);
    xpose_kernel<<<dim3(16, 4, 64), 256, 0, stream>>>(x, xp);
    for (int t = 0; t < 32; ++t) {
        step_kernel<<<512, 256, 0, stream>>>(
            xp + (size_t)t * 262144,
            hp + (size_t)(t & 1) * 262144,
            hp + (size_t)((t + 1) & 1) * 262144,
            Wt, bi4, cst4,
            hsT + (size_t)t * 2048 * 512);
    }
    oxpose_kernel<<<4096, 256, 0, stream>>>(hsT, out);
}